// Round 3
// baseline (152.815 us; speedup 1.0000x reference)
//
#include <hip/hip_runtime.h>

#define EPS 1e-7f
#define BATCH 8
#define NPT 2048   // points per batch
#define NFEAT 6
#define LOG2E 1.44269504088896340736f
#define RPB 8      // rows per block

typedef float vf4 __attribute__((ext_vector_type(4)));

// R3 DIAGNOSTIC PROBE #2 — intentional regression, buys the kernel's true duration.
// R2's duplicate-store probe was absorbed by L2 (same lines rewritten -> no extra
// HBM traffic, delta ~= 0). Robust fact across R0-R2: dur_us - top_fill ~= 59us,
// consistent with EITHER kernel~=24us + ~35us harness tiny-resets (roofline) OR
// kernel~=60us with an unexplained ~35us pathology. This probe runs the entire
// main loop TWICE inside ONE dispatch (opaque asm forces full VALU recompute,
// memory clobber keeps rep-0 stores). If kernel is slow (~60us non-write-bound),
// the dispatch lands at ~110-120us -> tops the rocprof table WITH counters.
// If fast (~24us), dispatch ~45us stays hidden and dur_us rises only ~+25.
// Values are bit-identical -> correctness unchanged.
__global__ __launch_bounds__(512)
void wij_fused_kernel(const float* __restrict__ emb,
                      const float* __restrict__ alpha,
                      const float* __restrict__ beta,
                      const float* __restrict__ radius,
                      float* __restrict__ out) {
    __shared__ float spow[NPT];   // pow row for this batch
    __shared__ float sred[8];     // per-wave mins

    int blk = blockIdx.x;                      // 0 .. BATCH*NPT/RPB - 1
    int b  = blk >> 8;                         // / (NPT/RPB) = /256
    int n0 = (blk & 255) * RPB;

    const float* base = emb + (size_t)b * NFEAT * NPT;
    int t = threadIdx.x;

    // ---- pow + min (redundant per block, trivial cost) ----
    float a2 = 2.0f * alpha[0];
    vf4 pm = ((const vf4*)(base + 4 * NPT))[t];
    vf4 pw;
    pw.x = __builtin_amdgcn_exp2f(a2 * __log2f(pm.x));
    pw.y = __builtin_amdgcn_exp2f(a2 * __log2f(pm.y));
    pw.z = __builtin_amdgcn_exp2f(a2 * __log2f(pm.z));
    pw.w = __builtin_amdgcn_exp2f(a2 * __log2f(pm.w));
    ((vf4*)spow)[t] = pw;

    float lmin = fminf(fminf(pw.x, pw.y), fminf(pw.z, pw.w));
    for (int off = 32; off > 0; off >>= 1)
        lmin = fminf(lmin, __shfl_down(lmin, off, 64));
    if ((t & 63) == 0) sred[t >> 6] = lmin;
    __syncthreads();
    float dmin = fminf(fminf(fminf(sred[0], sred[1]), fminf(sred[2], sred[3])),
                       fminf(fminf(sred[4], sred[5]), fminf(sred[6], sred[7]))) + EPS;

    // ---- fold scalars: w = exp2(beff2 - cb * |c_n-c_m|^2 * min(pn,pm)) ----
    float r  = radius[0];
    float bt = beta[0];
    float beff2 = bt * bt * 1e-4f * LOG2E;           // beta^2/1e4 in base-2
    float cb = beff2 / (dmin * (r * r + EPS));       // one divide per thread, off hot path

    // ---- column fragments ----
    vf4 cx = ((const vf4*)(base + 1 * NPT))[t];
    vf4 cy = ((const vf4*)(base + 2 * NPT))[t];

    // ---- row scalars ----
    float xn[RPB], yn[RPB], pn[RPB];
    #pragma unroll
    for (int rI = 0; rI < RPB; ++rI) {
        xn[rI] = base[1 * NPT + n0 + rI];
        yn[rI] = base[2 * NPT + n0 + rI];
        pn[rI] = spow[n0 + rI];
    }

    vf4* outp = (vf4*)(out + (size_t)(b * NPT + n0) * NPT) + t;

    // ---- main loop, executed twice (diagnostic duplication) ----
    #pragma unroll 1
    for (int rep = 0; rep < 2; ++rep) {
        #pragma unroll
        for (int rI = 0; rI < RPB; ++rI) {
            // Opaque pass-through: compiler cannot prove these equal rep-0's
            // values, so ALL dependent VALU work (dx/dy/da/exp2) re-executes.
            float xr = xn[rI], yr = yn[rI], pr = pn[rI];
            asm volatile("" : "+v"(xr), "+v"(yr), "+v"(pr));
            vf4 w;
            {
                float dx = xr - cx.x, dy = yr - cy.x;
                float da = (dx * dx + dy * dy) * fminf(pr, pw.x);
                w.x = __builtin_amdgcn_exp2f(beff2 - cb * da);
            }
            {
                float dx = xr - cx.y, dy = yr - cy.y;
                float da = (dx * dx + dy * dy) * fminf(pr, pw.y);
                w.y = __builtin_amdgcn_exp2f(beff2 - cb * da);
            }
            {
                float dx = xr - cx.z, dy = yr - cy.z;
                float da = (dx * dx + dy * dy) * fminf(pr, pw.z);
                w.z = __builtin_amdgcn_exp2f(beff2 - cb * da);
            }
            {
                float dx = xr - cx.w, dy = yr - cy.w;
                float da = (dx * dx + dy * dy) * fminf(pr, pw.w);
                w.w = __builtin_amdgcn_exp2f(beff2 - cb * da);
            }
            outp[(size_t)rI * (NPT / 4)] = w;
        }
        // Keep rep-0 stores observable (no dead-store elimination across reps).
        asm volatile("" ::: "memory");
    }
}

extern "C" void kernel_launch(void* const* d_in, const int* in_sizes, int n_in,
                              void* d_out, int out_size, void* d_ws, size_t ws_size,
                              hipStream_t stream) {
    const float* emb    = (const float*)d_in[0];
    const float* alpha  = (const float*)d_in[1];
    const float* beta   = (const float*)d_in[2];
    const float* radius = (const float*)d_in[3];
    float* out = (float*)d_out;
    (void)d_ws; (void)ws_size;

    wij_fused_kernel<<<(BATCH * NPT) / RPB, 512, 0, stream>>>(emb, alpha, beta, radius, out);
}

// Round 4
// 139.953 us; speedup vs baseline: 1.0919x; 1.0919x over previous
//
#include <hip/hip_runtime.h>

#define EPS 1e-7f
#define BATCH 8
#define NPT 2048   // points per batch
#define NFEAT 6
#define LOG2E 1.44269504088896340736f
#define RPB 8      // rows per block

typedef float vf4 __attribute__((ext_vector_type(4)));

// FINAL (revert of R3 diagnostic probe to the best measured variant, R1).
//
// Evidence trail:
//  R0->R1: NT store -> regular store: neutral (store cache policy exonerated).
//  R2: duplicate-store probe: absorbed by L2, delta ~0 (store ISSUE is free).
//  R3: full compute+store doubling probe: +11.8us only, doubled kernel still
//      < 81us -> single-pass kernel ~= 24us, within ~10% of its 134MB/6.3TB/s
//      write-drain roofline (21.3us). dur_us=141 decomposes as harness poison
//      fill (~81-86us) + harness tiny reset dispatches (~35us) + kernel (~24us).
//      Remaining kernel headroom ~2-3us < fill noise (+-5us): at the roofline.
//
// Structure: single fused kernel, one dispatch. Each block handles RPB=8
// consecutive rows of one batch. Blocks redundantly compute pow=momentum^(2a)
// for their whole batch (4 vals/thread), stage in LDS, block-reduce the min —
// no precompute kernel, no workspace. All scalar algebra folded so the inner
// loop is: 2 sub, 2 fma, 1 min, 1 mul, 1 fma, 1 exp2 per element, then one
// float4 store per 16 elements.
__global__ __launch_bounds__(512)
void wij_fused_kernel(const float* __restrict__ emb,
                      const float* __restrict__ alpha,
                      const float* __restrict__ beta,
                      const float* __restrict__ radius,
                      float* __restrict__ out) {
    __shared__ float spow[NPT];   // pow row for this batch
    __shared__ float sred[8];     // per-wave mins

    int blk = blockIdx.x;                      // 0 .. BATCH*NPT/RPB - 1
    int b  = blk >> 8;                         // / (NPT/RPB) = /256
    int n0 = (blk & 255) * RPB;

    const float* base = emb + (size_t)b * NFEAT * NPT;
    int t = threadIdx.x;

    // ---- pow + min (redundant per block, trivial cost) ----
    float a2 = 2.0f * alpha[0];
    vf4 pm = ((const vf4*)(base + 4 * NPT))[t];
    vf4 pw;
    pw.x = __builtin_amdgcn_exp2f(a2 * __log2f(pm.x));
    pw.y = __builtin_amdgcn_exp2f(a2 * __log2f(pm.y));
    pw.z = __builtin_amdgcn_exp2f(a2 * __log2f(pm.z));
    pw.w = __builtin_amdgcn_exp2f(a2 * __log2f(pm.w));
    ((vf4*)spow)[t] = pw;

    float lmin = fminf(fminf(pw.x, pw.y), fminf(pw.z, pw.w));
    for (int off = 32; off > 0; off >>= 1)
        lmin = fminf(lmin, __shfl_down(lmin, off, 64));
    if ((t & 63) == 0) sred[t >> 6] = lmin;
    __syncthreads();
    float dmin = fminf(fminf(fminf(sred[0], sred[1]), fminf(sred[2], sred[3])),
                       fminf(fminf(sred[4], sred[5]), fminf(sred[6], sred[7]))) + EPS;

    // ---- fold scalars: w = exp2(beff2 - cb * |c_n-c_m|^2 * min(pn,pm)) ----
    float r  = radius[0];
    float bt = beta[0];
    float beff2 = bt * bt * 1e-4f * LOG2E;           // beta^2/1e4 in base-2
    float cb = beff2 / (dmin * (r * r + EPS));       // one divide per thread, off hot path

    // ---- column fragments ----
    vf4 cx = ((const vf4*)(base + 1 * NPT))[t];
    vf4 cy = ((const vf4*)(base + 2 * NPT))[t];

    // ---- row scalars ----
    float xn[RPB], yn[RPB], pn[RPB];
    #pragma unroll
    for (int rI = 0; rI < RPB; ++rI) {
        xn[rI] = base[1 * NPT + n0 + rI];
        yn[rI] = base[2 * NPT + n0 + rI];
        pn[rI] = spow[n0 + rI];
    }

    vf4* outp = (vf4*)(out + (size_t)(b * NPT + n0) * NPT) + t;
    #pragma unroll
    for (int rI = 0; rI < RPB; ++rI) {
        vf4 w;
        {
            float dx = xn[rI] - cx.x, dy = yn[rI] - cy.x;
            float da = (dx * dx + dy * dy) * fminf(pn[rI], pw.x);
            w.x = __builtin_amdgcn_exp2f(beff2 - cb * da);
        }
        {
            float dx = xn[rI] - cx.y, dy = yn[rI] - cy.y;
            float da = (dx * dx + dy * dy) * fminf(pn[rI], pw.y);
            w.y = __builtin_amdgcn_exp2f(beff2 - cb * da);
        }
        {
            float dx = xn[rI] - cx.z, dy = yn[rI] - cy.z;
            float da = (dx * dx + dy * dy) * fminf(pn[rI], pw.z);
            w.z = __builtin_amdgcn_exp2f(beff2 - cb * da);
        }
        {
            float dx = xn[rI] - cx.w, dy = yn[rI] - cy.w;
            float da = (dx * dx + dy * dy) * fminf(pn[rI], pw.w);
            w.w = __builtin_amdgcn_exp2f(beff2 - cb * da);
        }
        outp[(size_t)rI * (NPT / 4)] = w;
    }
}

extern "C" void kernel_launch(void* const* d_in, const int* in_sizes, int n_in,
                              void* d_out, int out_size, void* d_ws, size_t ws_size,
                              hipStream_t stream) {
    const float* emb    = (const float*)d_in[0];
    const float* alpha  = (const float*)d_in[1];
    const float* beta   = (const float*)d_in[2];
    const float* radius = (const float*)d_in[3];
    float* out = (float*)d_out;
    (void)d_ws; (void)ws_size;

    wij_fused_kernel<<<(BATCH * NPT) / RPB, 512, 0, stream>>>(emb, alpha, beta, radius, out);
}